// Round 18
// baseline (190.414 us; speedup 1.0000x reference)
//
#include <hip/hip_runtime.h>

#define NROW 8192
#define INF  512
#define OUTF 256
#define M_ELEM (NROW * OUTF)   // 2,097,152 f32 per output matrix

typedef __bf16 v8bf __attribute__((ext_vector_type(8)));
typedef __bf16 v4bf __attribute__((ext_vector_type(4)));
typedef float  v4f  __attribute__((ext_vector_type(4)));
typedef float  v2f  __attribute__((ext_vector_type(2)));

__device__ __forceinline__ v8bf cvt_bf8(v4f u0, v4f u1) {
  v8bf v;
  v[0]=(__bf16)u0[0]; v[1]=(__bf16)u0[1]; v[2]=(__bf16)u0[2]; v[3]=(__bf16)u0[3];
  v[4]=(__bf16)u1[0]; v[5]=(__bf16)u1[1]; v[6]=(__bf16)u1[2]; v[7]=(__bf16)u1[3];
  return v;
}

// ---------------------------------------------------------------------------
// Kernel A: seq = feat @ W^T, bf16 MFMA, output in B-fragment-packed layout:
//   elem(m,o) -> (((m>>5)*16 + (o>>4))*64 + ((m>>3)&3)*16 + (o&15))*8 + (m&7)
// ---------------------------------------------------------------------------
__global__ __launch_bounds__(256) void seq_fts_kernel(
    const float* __restrict__ feat, const float* __restrict__ W,
    __bf16* __restrict__ Bp) {
  const int tid  = threadIdx.x;
  const int lane = tid & 63, w = tid >> 6;
  const int llo  = lane & 15, lhi = lane >> 4;
  const int row0 = blockIdx.x * 64;
  const int col0 = w * 64;

  v4f acc[4][4] = {};
#pragma unroll 1
  for (int kb = 0; kb < INF / 32; ++kb) {
    const int kofs = kb * 32 + lhi * 8;
    v8bf a[4], b[4];
#pragma unroll
    for (int i = 0; i < 4; ++i) {
      const float* p = feat + (size_t)(row0 + i * 16 + llo) * INF + kofs;
      a[i] = cvt_bf8(*(const v4f*)p, *(const v4f*)(p + 4));
    }
#pragma unroll
    for (int i = 0; i < 4; ++i) {
      const float* p = W + (size_t)(col0 + i * 16 + llo) * INF + kofs;
      b[i] = cvt_bf8(*(const v4f*)p, *(const v4f*)(p + 4));
    }
#pragma unroll
    for (int ri = 0; ri < 4; ++ri)
#pragma unroll
      for (int ci = 0; ci < 4; ++ci)
        acc[ri][ci] = __builtin_amdgcn_mfma_f32_16x16x32_bf16(
            a[ri], b[ci], acc[ri][ci], 0, 0, 0);
  }
#pragma unroll
  for (int ri = 0; ri < 4; ++ri)
#pragma unroll
    for (int ci = 0; ci < 4; ++ci) {
      const int mf = row0 + ri * 16 + lhi * 4;
      const int o  = col0 + ci * 16 + llo;
      size_t e = (((size_t)(mf >> 5) * 16 + (o >> 4)) * 64 +
                  ((mf >> 3) & 3) * 16 + (o & 15)) * 8 + (mf & 7);
      v4bf v;
      v[0] = (__bf16)acc[ri][ci][0]; v[1] = (__bf16)acc[ri][ci][1];
      v[2] = (__bf16)acc[ri][ci][2]; v[3] = (__bf16)acc[ri][ci][3];
      *(v4bf*)(Bp + e) = v;
    }
}

// ---------------------------------------------------------------------------
// Kernel B: partial[z,y] = adj_z[128 rows, K-half] @ seq.
// R17 discipline (reg-staged NT A, XOR key ((r&15)<<1)|((r>>3)&1), rolling
// 2-deep b regs, no B duplication across waves, one raw barrier/step) with
// BM=128 + BK=128 + K-split S=2: halves the B stream (1 GB -> 512 MB of
// L2/LLC traffic) at unchanged grid utilization (64x2x2 = 256 = 1/CU).
// A extents drop to 512 B contiguous/row (dose between R8's 128 B and R9's
// 1 KB). LDS: 2 x (128 rows x 512 B) = 128 KB.
// ---------------------------------------------------------------------------
__global__ __launch_bounds__(512, 2)
__attribute__((amdgpu_waves_per_eu(2, 2)))
void gcn_agg_kernel(
    const float* __restrict__ adjA, const float* __restrict__ adjB,
    const __bf16* __restrict__ Bp, float* __restrict__ P,
    int S, int nsteps) {
  const int tid  = threadIdx.x;
  const int lane = tid & 63, w = tid >> 6;   // wave w -> cols [w*32, w*32+32)
  const int llo  = lane & 15, lhi = lane >> 4;
  const int row0 = blockIdx.x * 128;
  const int y    = blockIdx.y;               // K-slice
  const int z    = blockIdx.z;
  const float* __restrict__ adj = z ? adjB : adjA;
  const int k0   = y * nsteps * 128;         // element-k base
  const int kk0  = y * nsteps * 4;           // 32-k chunk base

  __shared__ __align__(16) char LdsA[2][65536];   // 2 x (128 rows x 512 B)

  v4f acc[8][2] = {};        // 64 VGPR

  // --- A: 16 rows/wave, one 512 B extent per row (dwordx2 per lane, NT).
  v2f areg[16];
  auto issue_a = [&](int t) {
#pragma unroll
    for (int i = 0; i < 16; ++i) {
      const int r = w * 16 + i;
      const float* src =
          adj + (size_t)(row0 + r) * NROW + k0 + t * 128 + (lane << 1);
      areg[i] = __builtin_nontemporal_load((const v2f*)src);
    }
  };
  // swizzled write: lane l's 8 B -> row r, 16B-slot ((l>>1)^key), half (l&1).
  auto write_a = [&](int buf) {
#pragma unroll
    for (int i = 0; i < 16; ++i) {
      const int r   = w * 16 + i;
      const int key = ((r & 15) << 1) | ((r >> 3) & 1);
      const int byt = r * 512 + ((((lane >> 1) ^ key) << 4) | ((lane & 1) << 3));
      *(v2f*)(&LdsA[buf][byt]) = areg[i];
    }
  };

  // --- B fragments, kg granularity: [2 ci] = 16 VGPR (no duplication).
  const __bf16* __restrict__ Bpw = Bp + ((size_t)(w * 2) * 64 + lane) * 8;
  auto load_bg = [&](int t, int g, v8bf (&bb)[2]) {
#pragma unroll
    for (int ci = 0; ci < 2; ++ci)
      bb[ci] = *(const v8bf*)(
          Bpw + ((size_t)((kk0 + t * 4 + g) * 16 + ci)) * 512);
  };

  auto compute_g = [&](int buf, int kg, v8bf (&bb)[2]) {
    const char* ab = &LdsA[buf][0];
    v8bf af[8];
#pragma unroll
    for (int rt = 0; rt < 8; ++rt) {
      const int r   = rt * 16 + llo;
      const int key = ((r & 15) << 1) | ((r >> 3) & 1);
      const char* base = ab + r * 512;
      const int s0 = kg * 8 + lhi * 2;
      v4f u0 = *(const v4f*)(base + (((s0    ) ^ key) << 4));
      v4f u1 = *(const v4f*)(base + (((s0 + 1) ^ key) << 4));
      af[rt] = cvt_bf8(u0, u1);
    }
#pragma unroll
    for (int ci = 0; ci < 2; ++ci)
#pragma unroll
      for (int rt = 0; rt < 8; ++rt)
        acc[rt][ci] = __builtin_amdgcn_mfma_f32_16x16x32_bf16(
            af[rt], bb[ci], acc[rt][ci], 0, 0, 0);
  };

  // prologue: A(0) -> LDS[0]
  issue_a(0);
  asm volatile("s_waitcnt vmcnt(0)" ::: "memory");
  write_a(0);
  asm volatile("s_waitcnt lgkmcnt(0)" ::: "memory");
  __builtin_amdgcn_s_barrier();

  v8bf b[2][2];
#pragma unroll 1
  for (int t = 0; t < nsteps; ++t) {
    load_bg(t, 0, b[0]);                       // oldest in FIFO
    __builtin_amdgcn_sched_barrier(0);
    load_bg(t, 1, b[1]);
    __builtin_amdgcn_sched_barrier(0);
    if (t + 1 < nsteps) issue_a(t + 1);        // newest: B-waits never drain it
    __builtin_amdgcn_sched_barrier(0);
#pragma unroll
    for (int kg = 0; kg < 4; ++kg) {
      compute_g(t & 1, kg, b[kg & 1]);
      if (kg + 2 < 4) {
        __builtin_amdgcn_sched_barrier(0);
        load_bg(t, kg + 2, b[kg & 1]);
        __builtin_amdgcn_sched_barrier(0);
      }
    }
    __builtin_amdgcn_sched_barrier(0);
    if (t + 1 < nsteps) {
      asm volatile("s_waitcnt vmcnt(0)" ::: "memory");  // A(t+1) landed
      write_a((t + 1) & 1);
      asm volatile("s_waitcnt lgkmcnt(0)" ::: "memory");
    }
    __builtin_amdgcn_s_barrier();
  }

  // raw partial sums (bias/prelu in the reduce epilogue)
  float* __restrict__ Pp = P + (size_t)(z * S + y) * M_ELEM;
#pragma unroll
  for (int ci = 0; ci < 2; ++ci) {
    const int o = w * 32 + ci * 16 + llo;
#pragma unroll
    for (int rt = 0; rt < 8; ++rt) {
      const int m = row0 + rt * 16 + lhi * 4;
#pragma unroll
      for (int r = 0; r < 4; ++r)
        Pp[(size_t)(m + r) * OUTF + o] = acc[rt][ci][r];
    }
  }
}

// ---------------------------------------------------------------------------
// Epilogue: out = prelu(sum_y partial[z,y] + bias). v4f, grid-stride.
// For S==1, P == out (in-place bias+prelu).
// ---------------------------------------------------------------------------
__global__ __launch_bounds__(256) void reduce_kernel(
    const float* __restrict__ P, const float* __restrict__ bias,
    const float* __restrict__ prelu_a, float* __restrict__ out, int S) {
  const float slope = prelu_a[0];
  const int nv4 = 2 * M_ELEM / 4;
  for (int v = blockIdx.x * 256 + threadIdx.x; v < nv4; v += gridDim.x * 256) {
    const int z = v >> 19;                       // 524288 v4 per matrix
    const size_t r = (size_t)(v & 524287) * 4;
    const int o = (int)(r & 255);
    v4f s = {};
    for (int yy = 0; yy < S; ++yy)
      s += *(const v4f*)(P + (size_t)(z * S + yy) * M_ELEM + r);
    v4f b4 = *(const v4f*)(bias + o);
    s += b4;
    v4f res;
#pragma unroll
    for (int i = 0; i < 4; ++i) res[i] = s[i] >= 0.f ? s[i] : slope * s[i];
    *(v4f*)(out + (size_t)z * M_ELEM + r) = res;
  }
}

extern "C" void kernel_launch(void* const* d_in, const int* in_sizes, int n_in,
                              void* d_out, int out_size, void* d_ws, size_t ws_size,
                              hipStream_t stream) {
  const float* feat = (const float*)d_in[0];
  const float* adj  = (const float*)d_in[1];
  const float* aug  = (const float*)d_in[2];
  const float* W    = (const float*)d_in[3];
  const float* bias = (const float*)d_in[4];
  const float* pa   = (const float*)d_in[5];
  float* out = (float*)d_out;
  __bf16* Bp = (__bf16*)d_ws;                    // 4 MB packed seq_fts

  const size_t MB = 1ull << 20;
  int S = (ws_size >= 4 * MB + 2 * 2 * (size_t)M_ELEM * 4) ? 2 : 1;  // 36 MB
  float* P = (S == 1) ? out : (float*)((char*)d_ws + 4 * MB);
  const int nsteps = NROW / 128 / S;             // 32 (S=2) or 64 (S=1)

  seq_fts_kernel<<<dim3(NROW / 64), 256, 0, stream>>>(feat, W, Bp);
  gcn_agg_kernel<<<dim3(NROW / 128, S, 2), 512, 0, stream>>>(
      adj, aug, Bp, P, S, nsteps);
  reduce_kernel<<<dim3(1024), 256, 0, stream>>>(P, bias, pa, out, S);
}